// Round 8
// baseline (353.245 us; speedup 1.0000x reference)
//
#include <hip/hip_runtime.h>

typedef _Float16 half8  __attribute__((ext_vector_type(8)));
typedef _Float16 half4  __attribute__((ext_vector_type(4)));
typedef float    float4v __attribute__((ext_vector_type(4)));
typedef float    float8v __attribute__((ext_vector_type(8)));

#define N_ROWS  65536   // 64*32*32
#define N_CODES 1024
#define DIM     256
#define BM      64      // rows per block (screen / fallback)
#define BM2     16      // rows per block (backstop exact)
#define NBLKS   (N_ROWS / BM)   // 1024

// merge two sorted top-3 triples (values; indices for top-2), lowest-index on ties
__device__ __forceinline__ void merge3(float& m1, int& i1, float& m2, int& i2, float& m3,
                                       float o1, int oi1, float o2, int oi2, float o3) {
    if (o1 < m1 || (o1 == m1 && oi1 < i1)) {
        float t1 = m1; int ti1 = i1; float t2 = m2; int ti2 = i2; float t3 = m3;
        m1 = o1; i1 = oi1; m2 = o2; i2 = oi2; m3 = o3;
        o1 = t1; oi1 = ti1; o2 = t2; oi2 = ti2; o3 = t3;
    }
    // (m1,i1) is global best; 2nd = min(m2, o1)
    if (o1 < m2 || (o1 == m2 && oi1 < i2)) {
        m3 = fminf(m2, o2);
        m2 = o1; i2 = oi1;
    } else {
        m3 = fminf(m3, o1);
    }
}

// ---- prep: one wave per code. ||e||^2 and hi/lo f16 split written in MFMA
// B-fragment order (16x16x32): frag block b = nt*8 + ks holds 1024 halves:
// [hi 512][lo 512], chunk p = quad*16 + l15 -> code = nt*16+l15,
// k = ks*32 + quad*8 + j.  Also resets the backstop counter.
__global__ __launch_bounds__(64)
void vq_prep(const float* __restrict__ emb, float* __restrict__ e_norm,
             _Float16* __restrict__ e_frag, int* __restrict__ count) {
    const int c = blockIdx.x, lane = threadIdx.x;
    const int l15 = c & 15, nt = c >> 4;
    if (count && c == 0 && lane == 0) *count = 0;
    float4v v = ((const float4v*)(emb + (size_t)c * DIM))[lane];
    half4 h, l;
    float ss = 0.f;
    #pragma unroll
    for (int j = 0; j < 4; ++j) {
        float x = v[j];
        ss += x * x;
        _Float16 hh = (_Float16)x;
        h[j] = hh;
        l[j] = (_Float16)(x - (float)hh);
    }
    const int ks = lane >> 3, q = (lane >> 1) & 3, jb = (lane & 1) * 4;
    _Float16* p = e_frag + ((size_t)(nt * 8 + ks)) * 1024 + (q * 16 + l15) * 8 + jb;
    *(half4*)p = h;
    *(half4*)(p + 512) = l;
    #pragma unroll
    for (int m = 32; m >= 1; m >>= 1) ss += __shfl_xor(ss, m, 64);
    if (lane == 0) e_norm[c] = ss;
}

// ---- phase 1: hh-only screen + inline 2-candidate exact resolve.
// Tracks per-row (m1,i1,m2,i2,m3). T = 2*error-bound. Cases:
//   m2-m1 >  T : i1 provably exact.
//   m3-m1 >  T >= m2-m1 : exact argmin in {i1,i2}; resolved inline with two
//                          fp32 dot products (z row + emb rows, L2-hot).
//   m3-m1 <= T : rare (<1%); row -> list2, fixed by vq_exact16 backstop.
__global__ __launch_bounds__(256, 2)
void vq_screen(const float* __restrict__ z,
               const _Float16* __restrict__ e_frag,
               const float* __restrict__ e_norm,
               const float* __restrict__ emb,
               float* __restrict__ zq,
               float* __restrict__ idxf,
               int* __restrict__ count2,
               int* __restrict__ list2) {
    __shared__ _Float16 sA[32 * 512];         // hi only: [mt*8+ks][512] = 32 KB
    __shared__ float    s_nrm[N_CODES];       // 4 KB
    __shared__ float    s_znrm[BM];
    __shared__ float    s_red[4];
    __shared__ float4   s_best4[BM][5];       // (m1, i1, m2, i2) per wave slot
    __shared__ float    s_b3[BM][5];          // m3 per wave slot
    __shared__ int      s_idx[BM];
    __shared__ int      s_crow[BM], s_cc1[BM], s_cc2[BM];
    __shared__ int      s_ccnt;

    const int t = threadIdx.x;
    const int w = t >> 6, lane = t & 63, quad = lane >> 4, l15 = lane & 15;
    const int rowblk = blockIdx.x * BM;

    if (t == 0) s_ccnt = 0;

    float n0 = e_norm[t], n1 = e_norm[t + 256], n2 = e_norm[t + 512], n3 = e_norm[t + 768];
    s_nrm[t] = n0; s_nrm[t + 256] = n1; s_nrm[t + 512] = n2; s_nrm[t + 768] = n3;
    float mx = fmaxf(fmaxf(n0, n1), fmaxf(n2, n3));
    #pragma unroll
    for (int m = 1; m < 64; m <<= 1) mx = fmaxf(mx, __shfl_xor(mx, m, 64));
    if (lane == 0) s_red[w] = mx;

    // ---- stage A (hi only) + per-row ||z||^2; conflict-free LDS writes.
    float ss = 0.f;
    #pragma unroll
    for (int i = 0; i < 8; ++i) {
        const int row = w * 16 + l15;
        const int col = i * 32 + quad * 8;
        float8v v = *(const float8v*)(z + (size_t)(rowblk + row) * DIM + col);
        half8 h;
        #pragma unroll
        for (int j = 0; j < 8; ++j) {
            float x = v[j];
            ss += x * x;
            h[j] = (_Float16)x;
        }
        *(half8*)(sA + (size_t)(w * 8 + i) * 512 + lane * 8) = h;
    }
    ss += __shfl_xor(ss, 16, 64);
    ss += __shfl_xor(ss, 32, 64);
    if (quad == 0) s_znrm[w * 16 + l15] = ss;
    __syncthreads();   // the only compute barrier

    for (int pass = 0; pass < 2; ++pass) {
        const int ntbase = w * 16 + pass * 8;
        float4v acc[4][8] = {};

        #pragma unroll
        for (int ks = 0; ks < 8; ++ks) {
            half8 bh[8];
            #pragma unroll
            for (int nt = 0; nt < 8; ++nt)
                bh[nt] = *(const half8*)(e_frag + ((size_t)((ntbase + nt) * 8 + ks)) * 1024 + lane * 8);
            __builtin_amdgcn_s_setprio(1);
            #pragma unroll
            for (int mt = 0; mt < 4; ++mt) {
                half8 ah = *(const half8*)(sA + (size_t)(mt * 8 + ks) * 512 + lane * 8);
                #pragma unroll
                for (int nt = 0; nt < 8; ++nt)
                    acc[mt][nt] = __builtin_amdgcn_mfma_f32_16x16x32_f16(ah, bh[nt], acc[mt][nt], 0, 0, 0);
            }
            __builtin_amdgcn_s_setprio(0);
        }

        // ---- epilogue: per-row top-3 over this wave's 128 codes.
        // C/D layout: col = lane&15, row = quad*4 + reg.
        float nrm[8]; int cg[8];
        #pragma unroll
        for (int nt = 0; nt < 8; ++nt) {
            cg[nt]  = (ntbase + nt) * 16 + l15;
            nrm[nt] = s_nrm[cg[nt]];
        }
        #pragma unroll
        for (int mt = 0; mt < 4; ++mt) {
            #pragma unroll
            for (int r = 0; r < 4; ++r) {
                float m1 = nrm[0] - 2.0f * acc[mt][0][r]; int i1 = cg[0];
                float m2 = 1e30f, m3 = 1e30f; int i2 = 0;
                #pragma unroll
                for (int nt = 1; nt < 8; ++nt) {       // ascending codes
                    float s = nrm[nt] - 2.0f * acc[mt][nt][r];
                    if (s < m1)      { m3 = m2; m2 = m1; i2 = i1; m1 = s; i1 = cg[nt]; }
                    else if (s < m2) { m3 = m2; m2 = s; i2 = cg[nt]; }
                    else if (s < m3) { m3 = s; }
                }
                #pragma unroll
                for (int m = 1; m < 16; m <<= 1) {     // merge 16 l15 lanes (same row)
                    float o1 = __shfl_xor(m1, m, 64);
                    int  oi1 = __shfl_xor(i1, m, 64);
                    float o2 = __shfl_xor(m2, m, 64);
                    int  oi2 = __shfl_xor(i2, m, 64);
                    float o3 = __shfl_xor(m3, m, 64);
                    merge3(m1, i1, m2, i2, m3, o1, oi1, o2, oi2, o3);
                }
                if (l15 == 0) {
                    const int row = mt * 16 + quad * 4 + r;
                    if (pass == 1) {
                        float4 pv = s_best4[row][w];
                        merge3(m1, i1, m2, i2, m3,
                               pv.x, (int)pv.y, pv.z, (int)pv.w, s_b3[row][w]);
                    }
                    float4 pr; pr.x = m1; pr.y = (float)i1; pr.z = m2; pr.w = (float)i2;
                    s_best4[row][w] = pr;
                    s_b3[row][w] = m3;
                }
            }
        }
    }
    __syncthreads();

    // ---- block reduce over 4 wave slots/row; classify
    if (t < BM) {
        float4 b0 = s_best4[t][0];
        float m1 = b0.x, m2 = b0.z, m3 = s_b3[t][0];
        int   i1 = (int)b0.y, i2 = (int)b0.w;
        #pragma unroll
        for (int s = 1; s < 4; ++s) {
            float4 bv = s_best4[t][s];
            merge3(m1, i1, m2, i2, m3, bv.x, (int)bv.y, bv.z, (int)bv.w, s_b3[t][s]);
        }
        s_idx[t] = i1;
        float emax = sqrtf(fmaxf(fmaxf(s_red[0], s_red[1]), fmaxf(s_red[2], s_red[3])));
        float T = 0.005f * sqrtf(s_znrm[t]) * emax + 0.05f;   // >= 2*error bound
        if (m2 - m1 <= T) {
            if (m3 - m1 <= T) {
                int pos = atomicAdd(count2, 1);       // rare: full rescore
                list2[pos] = rowblk + t;
            } else {
                int p = atomicAdd(&s_ccnt, 1);        // 2-candidate inline
                s_crow[p] = t; s_cc1[p] = i1; s_cc2[p] = i2;
            }
        }
    }
    __syncthreads();

    // ---- inline exact resolve: wave per candidate entry, fp32 dots
    {
        const int cc = s_ccnt;
        for (int e = w; e < cc; e += 4) {
            const int row = s_crow[e], c1 = s_cc1[e], c2 = s_cc2[e];
            float4v zz = ((const float4v*)(z + (size_t)(rowblk + row) * DIM))[lane];
            float4v e1 = ((const float4v*)(emb + (size_t)c1 * DIM))[lane];
            float4v e2 = ((const float4v*)(emb + (size_t)c2 * DIM))[lane];
            float d1 = 0.f, d2 = 0.f;
            #pragma unroll
            for (int j = 0; j < 4; ++j) { d1 += zz[j] * e1[j]; d2 += zz[j] * e2[j]; }
            #pragma unroll
            for (int m = 1; m < 64; m <<= 1) {
                d1 += __shfl_xor(d1, m, 64);
                d2 += __shfl_xor(d2, m, 64);
            }
            if (lane == 0) {
                float s1 = s_nrm[c1] - 2.0f * d1;
                float s2 = s_nrm[c2] - 2.0f * d2;
                int wnr = (s1 < s2) ? c1 : (s2 < s1) ? c2 : (c1 < c2 ? c1 : c2);
                s_idx[row] = wnr;
            }
        }
    }
    __syncthreads();

    if (t < BM) idxf[rowblk + t] = (float)s_idx[t];

    // ---- fused gather: 4 threads/row, 16 float4 each
    const float4v* emb4 = (const float4v*)emb;
    float4v* zq4 = (float4v*)zq;
    const int rr = t >> 2, cb = t & 3;
    const int code = s_idx[rr];
    #pragma unroll
    for (int i = 0; i < 16; ++i) {
        const int chunk = cb + i * 4;
        zq4[(size_t)(rowblk + rr) * 64 + chunk] = emb4[(size_t)code * 64 + chunk];
    }
}

// ---- backstop: exact hi/lo 3-sweep for the rare m3-within-T rows.
// BM2=16 rows/block, grid-stride; wave w covers codes w*256..+255 in 2
// passes of 8 nt (acc[8] = 32 AGPR). Small blocks -> low per-block latency.
__global__ __launch_bounds__(256, 2)
void vq_exact16(const float* __restrict__ z,
                const _Float16* __restrict__ e_frag,
                const float* __restrict__ e_norm,
                const float* __restrict__ emb,
                float* __restrict__ zq,
                float* __restrict__ idxf,
                const int* __restrict__ count2,
                const int* __restrict__ list2) {
    const int cnt = *count2;

    __shared__ _Float16 sA[8 * 2 * 512];      // [ks][hi|lo][512] = 16 KB
    __shared__ float    s_nrm[N_CODES];
    __shared__ float2   s_best[BM2][5];
    __shared__ int      s_idx[BM2], s_rows[BM2];

    const int t = threadIdx.x;
    const int w = t >> 6, lane = t & 63, quad = lane >> 4, l15 = lane & 15;

    if (blockIdx.x * BM2 >= cnt) return;

    s_nrm[t]       = e_norm[t];
    s_nrm[t + 256] = e_norm[t + 256];
    s_nrm[t + 512] = e_norm[t + 512];
    s_nrm[t + 768] = e_norm[t + 768];

    for (int base = blockIdx.x * BM2; base < cnt; base += gridDim.x * BM2) {
        __syncthreads();                       // protect sA/s_rows reuse
        if (t < BM2) {
            int slot = base + t;
            s_rows[t] = list2[slot < cnt ? slot : cnt - 1];
        }
        __syncthreads();

        // stage 16 rows, hi/lo: wave w does ks = w and w+4
        #pragma unroll
        for (int i = 0; i < 2; ++i) {
            const int ks = w + i * 4;
            const int grow = s_rows[l15];
            const int col = ks * 32 + quad * 8;
            float8v v = *(const float8v*)(z + (size_t)grow * DIM + col);
            half8 h, lo;
            #pragma unroll
            for (int j = 0; j < 8; ++j) {
                float x = v[j];
                _Float16 hh = (_Float16)x;
                h[j] = hh;
                lo[j] = (_Float16)(x - (float)hh);
            }
            _Float16* p = sA + (size_t)(ks * 2) * 512 + lane * 8;
            *(half8*)p = h;
            *(half8*)(p + 512) = lo;
        }
        __syncthreads();

        for (int pass = 0; pass < 2; ++pass) {
            const int ntbase = w * 16 + pass * 8;
            float4v acc[8] = {};

            #pragma unroll
            for (int ks = 0; ks < 8; ++ks) {
                half8 bh[8], bl[8];
                #pragma unroll
                for (int nt = 0; nt < 8; ++nt) {
                    const _Float16* bp = e_frag + ((size_t)((ntbase + nt) * 8 + ks)) * 1024 + lane * 8;
                    bh[nt] = *(const half8*)bp;
                    bl[nt] = *(const half8*)(bp + 512);
                }
                const _Float16* ap = sA + (size_t)(ks * 2) * 512 + lane * 8;
                half8 ah = *(const half8*)ap;
                half8 al = *(const half8*)(ap + 512);
                __builtin_amdgcn_s_setprio(1);
                #pragma unroll
                for (int nt = 0; nt < 8; ++nt)
                    acc[nt] = __builtin_amdgcn_mfma_f32_16x16x32_f16(ah, bh[nt], acc[nt], 0, 0, 0);
                #pragma unroll
                for (int nt = 0; nt < 8; ++nt)
                    acc[nt] = __builtin_amdgcn_mfma_f32_16x16x32_f16(ah, bl[nt], acc[nt], 0, 0, 0);
                #pragma unroll
                for (int nt = 0; nt < 8; ++nt)
                    acc[nt] = __builtin_amdgcn_mfma_f32_16x16x32_f16(al, bh[nt], acc[nt], 0, 0, 0);
                __builtin_amdgcn_s_setprio(0);
            }

            float nrm[8]; int cg[8];
            #pragma unroll
            for (int nt = 0; nt < 8; ++nt) {
                cg[nt]  = (ntbase + nt) * 16 + l15;
                nrm[nt] = s_nrm[cg[nt]];
            }
            #pragma unroll
            for (int r = 0; r < 4; ++r) {
                float bs = nrm[0] - 2.0f * acc[0][r]; int bi = cg[0];
                #pragma unroll
                for (int nt = 1; nt < 8; ++nt) {
                    float s = nrm[nt] - 2.0f * acc[nt][r];
                    if (s < bs) { bs = s; bi = cg[nt]; }
                }
                #pragma unroll
                for (int m = 1; m < 16; m <<= 1) {
                    float s2 = __shfl_xor(bs, m, 64);
                    int   i2 = __shfl_xor(bi, m, 64);
                    if (s2 < bs || (s2 == bs && i2 < bi)) { bs = s2; bi = i2; }
                }
                if (l15 == 0) {
                    const int row = quad * 4 + r;
                    if (pass == 0) {
                        float2 pr; pr.x = bs; pr.y = (float)bi;
                        s_best[row][w] = pr;
                    } else {
                        float2 pv = s_best[row][w];
                        if (bs < pv.x) {
                            float2 pr; pr.x = bs; pr.y = (float)bi;
                            s_best[row][w] = pr;
                        }
                    }
                }
            }
        }
        __syncthreads();

        if (t < BM2) {
            float2 p0 = s_best[t][0];
            float bs = p0.x, bi = p0.y;
            #pragma unroll
            for (int s = 1; s < 4; ++s) {
                float2 pv = s_best[t][s];
                if (pv.x < bs || (pv.x == bs && pv.y < bi)) { bs = pv.x; bi = pv.y; }
            }
            s_idx[t] = (int)bi;
            idxf[s_rows[t]] = bi;
        }
        __syncthreads();

        // gather: 16 threads/row, 4 float4 each
        const float4v* emb4 = (const float4v*)emb;
        float4v* zq4 = (float4v*)zq;
        const int rr = t >> 4, cb = t & 15;
        const int grow = s_rows[rr];
        const int code = s_idx[rr];
        #pragma unroll
        for (int i = 0; i < 4; ++i) {
            const int chunk = cb + i * 16;
            zq4[(size_t)grow * 64 + chunk] = emb4[(size_t)code * 64 + chunk];
        }
    }
}

// ============== fallback path (small workspace): R3 kernel verbatim ======
__global__ __launch_bounds__(256, 2)
void vq_main(const float* __restrict__ z,
             const _Float16* __restrict__ e_frag,
             const float* __restrict__ e_norm,
             const float* __restrict__ emb,
             float* __restrict__ zq,
             float* __restrict__ idxf,
             int fused_gather) {
    __shared__ _Float16 sA[32 * 2 * 512];
    __shared__ float    s_nrm[N_CODES];
    __shared__ float2   s_best[BM][5];
    __shared__ int      s_idx[BM];

    const int t = threadIdx.x;
    const int w = t >> 6, lane = t & 63, quad = lane >> 4, l15 = lane & 15;
    const int rowblk = blockIdx.x * BM;

    s_nrm[t]       = e_norm[t];
    s_nrm[t + 256] = e_norm[t + 256];
    s_nrm[t + 512] = e_norm[t + 512];
    s_nrm[t + 768] = e_norm[t + 768];

    #pragma unroll
    for (int i = 0; i < 8; ++i) {
        const int row = w * 16 + l15;
        const int col = i * 32 + quad * 8;
        float8v v = *(const float8v*)(z + (size_t)(rowblk + row) * DIM + col);
        half8 h, lo;
        #pragma unroll
        for (int j = 0; j < 8; ++j) {
            float x = v[j];
            _Float16 hh = (_Float16)x;
            h[j] = hh;
            lo[j] = (_Float16)(x - (float)hh);
        }
        _Float16* p = sA + (size_t)((w * 8 + i) * 2) * 512 + lane * 8;
        *(half8*)p = h;
        *(half8*)(p + 512) = lo;
    }
    __syncthreads();

    for (int pass = 0; pass < 2; ++pass) {
        const int ntbase = w * 16 + pass * 8;
        float4v acc[4][8] = {};

        #pragma unroll
        for (int ks = 0; ks < 8; ++ks) {
            half8 bh[8], bl[8];
            #pragma unroll
            for (int nt = 0; nt < 8; ++nt) {
                const _Float16* bp = e_frag + ((size_t)((ntbase + nt) * 8 + ks)) * 1024 + lane * 8;
                bh[nt] = *(const half8*)bp;
                bl[nt] = *(const half8*)(bp + 512);
            }
            __builtin_amdgcn_s_setprio(1);
            #pragma unroll
            for (int mt = 0; mt < 4; ++mt) {
                const _Float16* ap = sA + (size_t)((mt * 8 + ks) * 2) * 512 + lane * 8;
                half8 ah = *(const half8*)ap;
                half8 al = *(const half8*)(ap + 512);
                #pragma unroll
                for (int nt = 0; nt < 8; ++nt)
                    acc[mt][nt] = __builtin_amdgcn_mfma_f32_16x16x32_f16(ah, bh[nt], acc[mt][nt], 0, 0, 0);
                #pragma unroll
                for (int nt = 0; nt < 8; ++nt)
                    acc[mt][nt] = __builtin_amdgcn_mfma_f32_16x16x32_f16(ah, bl[nt], acc[mt][nt], 0, 0, 0);
                #pragma unroll
                for (int nt = 0; nt < 8; ++nt)
                    acc[mt][nt] = __builtin_amdgcn_mfma_f32_16x16x32_f16(al, bh[nt], acc[mt][nt], 0, 0, 0);
            }
            __builtin_amdgcn_s_setprio(0);
        }

        float nrm[8]; int cg[8];
        #pragma unroll
        for (int nt = 0; nt < 8; ++nt) {
            cg[nt]  = (ntbase + nt) * 16 + l15;
            nrm[nt] = s_nrm[cg[nt]];
        }
        #pragma unroll
        for (int mt = 0; mt < 4; ++mt) {
            #pragma unroll
            for (int r = 0; r < 4; ++r) {
                float bs = nrm[0] - 2.0f * acc[mt][0][r]; int bi = cg[0];
                #pragma unroll
                for (int nt = 1; nt < 8; ++nt) {
                    float s = nrm[nt] - 2.0f * acc[mt][nt][r];
                    if (s < bs) { bs = s; bi = cg[nt]; }
                }
                #pragma unroll
                for (int m = 1; m < 16; m <<= 1) {
                    float s2 = __shfl_xor(bs, m, 64);
                    int   i2 = __shfl_xor(bi, m, 64);
                    if (s2 < bs || (s2 == bs && i2 < bi)) { bs = s2; bi = i2; }
                }
                if (l15 == 0) {
                    const int row = mt * 16 + quad * 4 + r;
                    if (pass == 0) {
                        float2 pr; pr.x = bs; pr.y = (float)bi;
                        s_best[row][w] = pr;
                    } else {
                        float2 pv = s_best[row][w];
                        if (bs < pv.x) {
                            float2 pr; pr.x = bs; pr.y = (float)bi;
                            s_best[row][w] = pr;
                        }
                    }
                }
            }
        }
    }
    __syncthreads();

    if (t < BM) {
        float2 p0 = s_best[t][0];
        float bs = p0.x, bi = p0.y;
        #pragma unroll
        for (int s = 1; s < 4; ++s) {
            float2 pv = s_best[t][s];
            if (pv.x < bs || (pv.x == bs && pv.y < bi)) { bs = pv.x; bi = pv.y; }
        }
        s_idx[t] = (int)bi;
        idxf[rowblk + t] = bi;
    }

    if (!fused_gather) return;
    __syncthreads();

    const float4v* emb4 = (const float4v*)emb;
    float4v* zq4 = (float4v*)zq;
    const int rr = t >> 2, cb = t & 3;
    const int code = s_idx[rr];
    #pragma unroll
    for (int i = 0; i < 16; ++i) {
        const int chunk = cb + i * 4;
        zq4[(size_t)(rowblk + rr) * 64 + chunk] = emb4[(size_t)code * 64 + chunk];
    }
}

__global__ __launch_bounds__(256)
void vq_gather(const float* __restrict__ emb,
               const float* __restrict__ idxf,
               float* __restrict__ zq) {
    const int tid  = blockIdx.x * 256 + threadIdx.x;
    const int r    = tid >> 6;
    const int lane = tid & 63;
    const int idx  = (int)idxf[r];
    const float4* ep = (const float4*)(emb + (size_t)idx * DIM);
    ((float4*)(zq + (size_t)r * DIM))[lane] = ep[lane];
}

extern "C" void kernel_launch(void* const* d_in, const int* in_sizes, int n_in,
                              void* d_out, int out_size, void* d_ws, size_t ws_size,
                              hipStream_t stream) {
    const float* z   = (const float*)d_in[0];   // (64,32,32,256) fp32
    const float* emb = (const float*)d_in[1];   // (1024,256) fp32

    float* zq   = (float*)d_out;                        // output 0
    float* idxf = zq + (size_t)N_ROWS * DIM;            // output 1

    const size_t efrag_sz = (size_t)N_CODES * DIM * 2 * sizeof(_Float16); // 1 MB
    const size_t list_sz  = (size_t)N_ROWS * sizeof(int);                 // 256 KB
    const size_t need_p   = 4096 + efrag_sz + 4096 + list_sz;

    if (ws_size >= need_p) {
        // screen + inline-resolve + tiny backstop
        float*    e_norm = (float*)d_ws;
        _Float16* e_frag = (_Float16*)((char*)d_ws + 4096);
        int*      count2 = (int*)((char*)d_ws + 4096 + efrag_sz);
        int*      list2  = (int*)((char*)d_ws + 4096 + efrag_sz + 4096);
        vq_prep<<<N_CODES, 64, 0, stream>>>(emb, e_norm, e_frag, count2);
        vq_screen<<<NBLKS, 256, 0, stream>>>(z, e_frag, e_norm, emb, zq, idxf, count2, list2);
        vq_exact16<<<512, 256, 0, stream>>>(z, e_frag, e_norm, emb, zq, idxf, count2, list2);
    } else {
        // fallback: measured-best R3 path
        const size_t need = 4096 + efrag_sz;
        const int in_ws = (ws_size >= need);
        char* base = in_ws ? (char*)d_ws : (char*)d_out;
        float*    e_norm = (float*)base;
        _Float16* e_frag = (_Float16*)(base + 4096);
        vq_prep<<<N_CODES, 64, 0, stream>>>(emb, e_norm, e_frag, (int*)0);
        vq_main<<<NBLKS, 256, 0, stream>>>(z, e_frag, e_norm, emb, zq, idxf, in_ws);
        if (!in_ws)
            vq_gather<<<(N_ROWS * 64) / 256, 256, 0, stream>>>(emb, idxf, zq);
    }
}